// Round 3
// baseline (1748.543 us; speedup 1.0000x reference)
//
#include <hip/hip_runtime.h>

#define BN_SCALE 0.9999950000374997f  // 1/sqrt(1+1e-5)

// ---------------- knn4: 4 queries/block; candidate sq-norm folded into dot loop.
// NOTE: the per-row constant -|q|^2 is dropped (top_k indices invariant to row shift).
// R = N/256 (points per thread). Dot phase is c-outer / m-inner register-blocked:
//  * q values loaded as uniform float4 -> s_load_dwordx4 (SGPR operand in fma, no LDS)
//  * candidate loads via uniform base + invariant thread offset -> saddr-form, no per-c
//    vector address math
// Accumulation order (ascending c, fmaf chain) and selection phase are IDENTICAL to the
// previous round -> indices bit-identical.
template <int R>
__global__ void knn4_kernel(const float* __restrict__ Q, int qStrideB,
                            const float* __restrict__ Xc, int cStrideB,
                            int C, int M, int N, int k, int* __restrict__ idxOut) {
  __shared__ float negd[4][R * 256];
  int b = blockIdx.y, q0 = blockIdx.x * 4, tid = threadIdx.x;
  const float* qb = Q + (long)b * qStrideB + q0;     // + c*M walks channels (uniform)
  const float* cb = Xc + (long)b * cStrideB;         // uniform
  float d0[R], d1[R], d2[R], d3[R], sq[R];
  #pragma unroll
  for (int i = 0; i < R; ++i) { d0[i] = d1[i] = d2[i] = d3[i] = sq[i] = 0.f; }
  for (int c = 0; c < C; ++c) {
    float4 q4 = *(const float4*)(qb + (long)c * M);  // uniform -> scalar load
    const float* pc = cb + (long)c * N;              // uniform base
    #pragma unroll
    for (int i = 0; i < R; ++i) {
      float xv = pc[tid + 256 * i];
      sq[i] = fmaf(xv, xv, sq[i]);
      d0[i] = fmaf(q4.x, xv, d0[i]);
      d1[i] = fmaf(q4.y, xv, d1[i]);
      d2[i] = fmaf(q4.z, xv, d2[i]);
      d3[i] = fmaf(q4.w, xv, d3[i]);
    }
  }
  #pragma unroll
  for (int i = 0; i < R; ++i) {
    int m = tid + 256 * i;
    negd[0][m] = 2.f * d0[i] - sq[i];
    negd[1][m] = 2.f * d1[i] - sq[i];
    negd[2][m] = 2.f * d2[i] - sq[i];
    negd[3][m] = 2.f * d3[i] - sq[i];
  }
  __syncthreads();
  int lane = tid & 63, w = tid >> 6;
  float* row = negd[w];
  int* outp = idxOut + ((long)b * M + (q0 + w)) * k;
  for (int kk = 0; kk < k; ++kk) {
    float best = -INFINITY; int bi = N;
    for (int m = lane; m < N; m += 64) {
      float v = row[m];
      if (v > best) { best = v; bi = m; }
    }
    for (int off = 32; off > 0; off >>= 1) {
      float ov = __shfl_xor(best, off);
      int   oi = __shfl_xor(bi, off);
      if (ov > best || (ov == best && oi < bi)) { best = ov; bi = oi; }
    }
    if (lane == (bi & 63)) row[bi] = -INFINITY;
    if (lane == 0) outp[kk] = bi;
  }
}

// ---------------- gemmPS: one pass computes BOTH halves of the edge-conv weight ----------------
__global__ void gemmPS_kernel(const float* __restrict__ X, int xStrideB, int C, int Np,
                              const float* __restrict__ W, int ldw, int O,
                              float* __restrict__ PtT, float* __restrict__ StT) {
  __shared__ float Wp[16][65];
  __shared__ float Ws[16][65];
  __shared__ float Xt[16][65];
  int b = blockIdx.z;
  int n0 = blockIdx.x * 64, o0 = blockIdx.y * 64;
  int tid = threadIdx.x;
  int to = tid % 16, tn = tid / 16;
  float accP[4][4] = {}, accS[4][4] = {};
  for (int c0 = 0; c0 < C; c0 += 16) {
    for (int e = tid; e < 16 * 64; e += 256) {
      int oo = e / 16, kk = e % 16;
      int c = c0 + kk, o = o0 + oo;
      bool ok = (c < C && o < O);
      Wp[kk][oo] = ok ? W[(long)o * ldw + c] : 0.f;
      Ws[kk][oo] = ok ? W[(long)o * ldw + C + c] : 0.f;
    }
    for (int e = tid; e < 16 * 64; e += 256) {
      int kk = e / 64, nn = e % 64;
      int c = c0 + kk, n = n0 + nn;
      Xt[kk][nn] = (c < C && n < Np) ? X[(long)b * xStrideB + (long)c * Np + n] : 0.f;
    }
    __syncthreads();
    for (int kk = 0; kk < 16; ++kk) {
      float xv[4], wp[4], ws[4];
      for (int i = 0; i < 4; ++i) xv[i] = Xt[kk][tn + 16 * i];
      for (int j = 0; j < 4; ++j) { wp[j] = Wp[kk][to + 16 * j]; ws[j] = Ws[kk][to + 16 * j]; }
      for (int i = 0; i < 4; ++i)
        for (int j = 0; j < 4; ++j) {
          accP[i][j] = fmaf(xv[i], wp[j], accP[i][j]);
          accS[i][j] = fmaf(xv[i], ws[j], accS[i][j]);
        }
    }
    __syncthreads();
  }
  for (int i = 0; i < 4; ++i) {
    int n = n0 + tn + 16 * i;
    if (n >= Np) continue;
    for (int j = 0; j < 4; ++j) {
      int o = o0 + to + 16 * j;
      if (o < O) {
        long off = ((long)b * Np + n) * O + o;
        PtT[off] = accP[i][j];
        StT[off] = accS[i][j];
      }
    }
  }
}

// ---------------- ecfinish ----------------
__global__ void ecfinish_kernel(const float* __restrict__ Pt, const float* __restrict__ St,
                                const int* __restrict__ idx, int k, int O, int Np,
                                const float* __restrict__ g, const float* __restrict__ bb,
                                float* __restrict__ outp, long oStrideB) {
  int b = blockIdx.y;
  int n = blockIdx.x * blockDim.y + threadIdx.y;
  int o = threadIdx.x;
  const float* PtB = Pt + (long)b * Np * O;
  const float* StB = St + (long)b * Np * O;
  const int* ip = idx + ((long)b * Np + n) * k;
  float mx = -INFINITY, mn = INFINITY;
  for (int kk = 0; kk < k; ++kk) {
    float v = PtB[(long)ip[kk] * O + o];
    mx = fmaxf(mx, v); mn = fminf(mn, v);
  }
  float ctrP = PtB[(long)n * O + o];
  float ctrS = StB[(long)n * O + o];
  float gs = g[o] * BN_SCALE;
  float m = (gs >= 0.f) ? mx : mn;
  float h = (ctrS - ctrP + m) * gs + bb[o];
  outp[(long)b * oStrideB + (long)o * Np + n] = h >= 0.f ? h : 0.2f * h;
}

// ---------------- gemm_colmax ----------------
__global__ void gemm_colmax_kernel(const float* __restrict__ X, int xStrideB, int C, int Np,
                                   const float* __restrict__ W, int ldw, int O,
                                   const float* __restrict__ g, const float* __restrict__ bb,
                                   float* __restrict__ partial) {
  __shared__ float Wt[16][65];
  __shared__ float Xt[16][65];
  int b = blockIdx.z;
  int n0 = blockIdx.x * 64, o0 = blockIdx.y * 64;
  int tid = threadIdx.x;
  int to = tid % 16, tn = tid / 16;
  float acc[4][4] = {};
  for (int c0 = 0; c0 < C; c0 += 16) {
    for (int e = tid; e < 16 * 64; e += 256) {
      int oo = e / 16, kk = e % 16;
      int c = c0 + kk, o = o0 + oo;
      Wt[kk][oo] = (c < C && o < O) ? W[(long)o * ldw + c] : 0.f;
    }
    for (int e = tid; e < 16 * 64; e += 256) {
      int kk = e / 64, nn = e % 64;
      int c = c0 + kk, n = n0 + nn;
      Xt[kk][nn] = (c < C && n < Np) ? X[(long)b * xStrideB + (long)c * Np + n] : 0.f;
    }
    __syncthreads();
    for (int kk = 0; kk < 16; ++kk) {
      float xv[4], wv[4];
      for (int i = 0; i < 4; ++i) xv[i] = Xt[kk][tn + 16 * i];
      for (int j = 0; j < 4; ++j) wv[j] = Wt[kk][to + 16 * j];
      for (int i = 0; i < 4; ++i)
        for (int j = 0; j < 4; ++j) acc[i][j] = fmaf(xv[i], wv[j], acc[i][j]);
    }
    __syncthreads();
  }
  float vm[4];
  for (int j = 0; j < 4; ++j) {
    int o = o0 + to + 16 * j;
    float gs = g[o] * BN_SCALE, bo = bb[o];
    float m = -INFINITY;
    for (int i = 0; i < 4; ++i) {
      float h = acc[i][j] * gs + bo;
      h = h >= 0.f ? h : 0.2f * h;
      m = fmaxf(m, h);
    }
    vm[j] = m;
  }
  for (int j = 0; j < 4; ++j) Xt[tn][to + 16 * j] = vm[j];
  __syncthreads();
  for (int s = 8; s > 0; s >>= 1) {
    if (tn < s)
      for (int j = 0; j < 4; ++j)
        Xt[tn][to + 16 * j] = fmaxf(Xt[tn][to + 16 * j], Xt[tn + s][to + 16 * j]);
    __syncthreads();
  }
  if (tn == 0)
    for (int j = 0; j < 4; ++j) {
      int o = o0 + to + 16 * j;
      partial[((long)b * gridDim.x + blockIdx.x) * O + o] = Xt[0][to + 16 * j];
    }
}

// ---------------- FPS: latency-optimized (DPP argmax, reg-resident points, coord broadcast).
template <int CTRL>
__device__ __forceinline__ float fps_dpp_max_step(float v) {
  int xi = __builtin_bit_cast(int, v);
  int ti = __builtin_amdgcn_update_dpp(xi, xi, CTRL, 0xf, 0xf, false);  // invalid lanes -> old(=v)
  return fmaxf(v, __builtin_bit_cast(float, ti));
}

__global__ void __launch_bounds__(256, 1) fps_kernel(const float* __restrict__ xyz, int N, int M,
                                                     int* __restrict__ fpsIdx, float* __restrict__ node1) {
  #pragma clang fp contract(off)
  __shared__ float4 sp4[2048];   // point n at slot (n&7)*256 + (n>>3)
  __shared__ int fidx[512];
  __shared__ float4 wvc[2][4];   // per-wave {gmax, x, y, z}, parity double-buffered
  __shared__ int   wis[2][4];
  int b = blockIdx.x, tid = threadIdx.x;
  int lane = tid & 63, w = tid >> 6;
  const float* xb = xyz + (long)b * 3 * N;
  for (int n = tid; n < N; n += 256) {
    sp4[((n & 7) << 8) | (n >> 3)] = make_float4(xb[n], xb[N + n], xb[2 * N + n], 0.f);
  }
  __syncthreads();
  float4 pt[8];
  #pragma unroll
  for (int i = 0; i < 8; ++i) pt[i] = sp4[(i << 8) | tid];   // point tid*8+i, resident in VGPRs
  float dist[8];
  #pragma unroll
  for (int i = 0; i < 8; ++i) dist[i] = 1e10f;
  int base = tid * 8;
  int last = 0;
  float4 l0 = sp4[0];            // point 0 (slot 0), broadcast read once
  float lx = l0.x, ly = l0.y, lz = l0.z;
  for (int it = 0; it < M; ++it) {
    int p = it & 1;
    if (tid == 0) fidx[it] = last;
    float best = -INFINITY; int bi = N;
    #pragma unroll
    for (int i = 0; i < 8; ++i) {
      float dx = pt[i].x - lx, dy = pt[i].y - ly, dz = pt[i].z - lz;
      float dx2 = dx * dx, dy2 = dy * dy, dz2 = dz * dz;
      float d = (dx2 + dy2) + dz2;
      float dn = dist[i];
      if (d < dn) dn = d;
      dist[i] = dn;
      if (dn > best) { best = dn; bi = base + i; }  // ascending -> first max in lane kept
    }
    // per-thread coords of its own best point (register select; off critical path)
    float cx = pt[0].x, cy = pt[0].y, cz = pt[0].z;
    #pragma unroll
    for (int i = 1; i < 8; ++i) {
      bool c = (bi == base + i);
      cx = c ? pt[i].x : cx; cy = c ? pt[i].y : cy; cz = c ? pt[i].z : cz;
    }
    // wave-wide exact max via DPP chain; full max lands in lane 63
    float v = best;
    v = fps_dpp_max_step<0x111>(v);  // row_shr:1
    v = fps_dpp_max_step<0x112>(v);  // row_shr:2
    v = fps_dpp_max_step<0x114>(v);  // row_shr:4
    v = fps_dpp_max_step<0x118>(v);  // row_shr:8
    v = fps_dpp_max_step<0x142>(v);  // row_bcast:15
    v = fps_dpp_max_step<0x143>(v);  // row_bcast:31
    float gmax = __builtin_bit_cast(float, __builtin_amdgcn_readlane(__builtin_bit_cast(int, v), 63));
    unsigned long long mm = __ballot(best == gmax);
    int srcLane = (int)(__ffsll((long long)mm) - 1);   // wave's first-occurrence argmax lane
    if (lane == srcLane) { wvc[p][w] = make_float4(gmax, cx, cy, cz); wis[p][w] = bi; }
    __syncthreads();
    // all threads redundantly combine the 4 wave results (waves ascend in index)
    float4 c0 = wvc[p][0], c1 = wvc[p][1], c2 = wvc[p][2], c3 = wvc[p][3];
    int i0 = wis[p][0], i1 = wis[p][1], i2 = wis[p][2], i3 = wis[p][3];
    float bv = c0.x; int bbi = i0; lx = c0.y; ly = c0.z; lz = c0.w;
    { bool c = (c1.x > bv) || (c1.x == bv && i1 < bbi);
      bv = c ? c1.x : bv; bbi = c ? i1 : bbi; lx = c ? c1.y : lx; ly = c ? c1.z : ly; lz = c ? c1.w : lz; }
    { bool c = (c2.x > bv) || (c2.x == bv && i2 < bbi);
      bv = c ? c2.x : bv; bbi = c ? i2 : bbi; lx = c ? c2.y : lx; ly = c ? c2.z : ly; lz = c ? c2.w : lz; }
    { bool c = (c3.x > bv) || (c3.x == bv && i3 < bbi);
      bv = c ? c3.x : bv; bbi = c ? i3 : bbi; lx = c ? c3.y : lx; ly = c ? c3.z : ly; lz = c ? c3.w : lz; }
    last = bbi;
    // parity: slot p rewritten only in iter it+2, after barrier it+1 -> safe with 1 barrier
  }
  for (int e = tid; e < M; e += 256) fpsIdx[(long)b * M + e] = fidx[e];
  for (int e = tid; e < 3 * M; e += 256) {
    int c = e / M, i = e % M;
    int src = fidx[i];
    float4 ptc = sp4[((src & 7) << 8) | (src >> 3)];
    node1[(long)b * 3 * M + e] = (c == 0) ? ptc.x : (c == 1) ? ptc.y : ptc.z;
  }
}

// ---------------- xmfill: fused nf1 gather + aggregate gathermax ----------------
__global__ void xmfill_kernel(const float* __restrict__ xt1, int N,
                              const int* __restrict__ fpsI,
                              const int* __restrict__ idxK, int k, int M,
                              float* __restrict__ xm, int B) {
  long t = (long)blockIdx.x * blockDim.x + threadIdx.x;
  long total = (long)B * 128 * M;
  if (t >= total) return;
  int i = (int)(t % M);
  int c = (int)((t / M) % 128);
  int b = (int)(t / ((long)128 * M));
  const float* xb = xt1 + (long)b * 128 * N + (long)c * N;
  float* xmB = xm + (long)b * 256 * M;
  xmB[(long)c * M + i] = xb[fpsI[(long)b * M + i]];
  const int* ip = idxK + ((long)b * M + i) * k;
  float best = -INFINITY;
  for (int kk = 0; kk < k; ++kk) best = fmaxf(best, xb[ip[kk]]);
  xmB[(long)(128 + c) * M + i] = best;
}

// ---------------- head: fused colmax_finish + 3-layer MLP ----------------
__global__ void head_kernel(const float* __restrict__ partA, int NTa,
                            const float* __restrict__ partB, int NTb,
                            const float* __restrict__ Wl1, const float* __restrict__ g6, const float* __restrict__ b6,
                            const float* __restrict__ Wl2, const float* __restrict__ bl2,
                            const float* __restrict__ g7, const float* __restrict__ b7,
                            const float* __restrict__ Wl3, const float* __restrict__ bl3,
                            float* __restrict__ logits) {
  __shared__ float v[2048];
  __shared__ float h1[512];
  __shared__ float h2[256];
  int b = blockIdx.x, tid = threadIdx.x;
  for (int o = tid; o < 1024; o += 256) {
    float m = -INFINITY;
    for (int t = 0; t < NTa; ++t) m = fmaxf(m, partA[((long)b * NTa + t) * 1024 + o]);
    v[o] = m;
    float m2 = -INFINITY;
    for (int t = 0; t < NTb; ++t) m2 = fmaxf(m2, partB[((long)b * NTb + t) * 1024 + o]);
    v[1024 + o] = m2;
  }
  __syncthreads();
  for (int o = tid; o < 512; o += 256) {
    const float* wr = Wl1 + (long)o * 2048;
    float s = 0.f;
    for (int c = 0; c < 2048; c += 4) {
      float4 w4 = *(const float4*)(wr + c);
      s = fmaf(w4.x, v[c], s); s = fmaf(w4.y, v[c + 1], s);
      s = fmaf(w4.z, v[c + 2], s); s = fmaf(w4.w, v[c + 3], s);
    }
    float h = s * (g6[o] * BN_SCALE) + b6[o];
    h1[o] = h >= 0.f ? h : 0.2f * h;
  }
  __syncthreads();
  for (int o = tid; o < 256; o += 256) {
    const float* wr = Wl2 + (long)o * 512;
    float s = 0.f;
    for (int c = 0; c < 512; c += 4) {
      float4 w4 = *(const float4*)(wr + c);
      s = fmaf(w4.x, h1[c], s); s = fmaf(w4.y, h1[c + 1], s);
      s = fmaf(w4.z, h1[c + 2], s); s = fmaf(w4.w, h1[c + 3], s);
    }
    s += bl2[o];
    float h = s * (g7[o] * BN_SCALE) + b7[o];
    h2[o] = h >= 0.f ? h : 0.2f * h;
  }
  __syncthreads();
  if (tid < 40) {
    const float* wr = Wl3 + (long)tid * 256;
    float s = 0.f;
    for (int c = 0; c < 256; ++c) s = fmaf(wr[c], h2[c], s);
    logits[(long)b * 40 + tid] = s + bl3[tid];
  }
}

extern "C" void kernel_launch(void* const* d_in, const int* in_sizes, int n_in,
                              void* d_out, int out_size, void* d_ws, size_t ws_size,
                              hipStream_t stream) {
  const float* x   = (const float*)d_in[0];
  const float* W1  = (const float*)d_in[1];
  const float* g1  = (const float*)d_in[2];
  const float* b1  = (const float*)d_in[3];
  const float* W2  = (const float*)d_in[4];
  const float* g2  = (const float*)d_in[5];
  const float* b2  = (const float*)d_in[6];
  const float* W2m = (const float*)d_in[7];
  const float* g2m = (const float*)d_in[8];
  const float* b2m = (const float*)d_in[9];
  const float* W3  = (const float*)d_in[10];
  const float* g3  = (const float*)d_in[11];
  const float* b3  = (const float*)d_in[12];
  const float* W4  = (const float*)d_in[13];
  const float* g4  = (const float*)d_in[14];
  const float* b4  = (const float*)d_in[15];
  const float* W5  = (const float*)d_in[16];
  const float* g5  = (const float*)d_in[17];
  const float* b5  = (const float*)d_in[18];
  const float* Wl1 = (const float*)d_in[19];
  const float* g6  = (const float*)d_in[20];
  const float* b6  = (const float*)d_in[21];
  const float* Wl2 = (const float*)d_in[22];
  const float* bl2 = (const float*)d_in[23];
  const float* g7  = (const float*)d_in[24];
  const float* b7  = (const float*)d_in[25];
  const float* Wl3 = (const float*)d_in[26];
  const float* bl3 = (const float*)d_in[27];
  float* outF = (float*)d_out;

  const int B = 8, N = 2048, K = 20, M = 512, K2 = 10;

  float* ws    = (float*)d_ws;
  float* xt1   = ws;                               // (B,128,N)
  float* xm    = xt1 + (size_t)B * 128 * N;        // (B,256,M)
  float* xc    = xm  + (size_t)B * 256 * M;        // (B,512,M)
  float* Pt    = xc  + (size_t)B * 512 * M;        // max(B*N*64, B*M*256)
  float* St    = Pt  + (size_t)B * N * 64;
  float* partA = St  + (size_t)B * N * 64;         // (B,32,1024)
  float* partB = partA + (size_t)B * 32 * 1024;    // (B,8,1024)
  int*   idxK  = (int*)(partB + (size_t)B * 8 * 1024);  // (B,N,K)
  int*   fpsI  = idxK + (size_t)B * N * K;         // (B,M)

  float* logits = outF;        // (B,40)
  float* node1  = outF + 320;  // (B,3,M)

  dim3 t256(256);

  // ---- stage 1: knn(xyz) + edge_conv1 -> xt1 ch 0..63
  knn4_kernel<8><<<dim3(N / 4, B), t256, 0, stream>>>(x, 3 * N, x, 3 * N, 3, N, N, K, idxK);
  gemmPS_kernel<<<dim3(N / 64, 1, B), t256, 0, stream>>>(x, 3 * N, 3, N, W1, 6, 64, Pt, St);
  ecfinish_kernel<<<dim3(N / 4, B), dim3(64, 4), 0, stream>>>(Pt, St, idxK, K, 64, N, g1, b1, xt1, (long)128 * N);

  // FPS (xyz only)
  fps_kernel<<<dim3(B), t256, 0, stream>>>(x, N, M, fpsI, node1);

  // ---- stage 2: knn(x1) + edge_conv2 -> xt1 ch 64..127
  knn4_kernel<8><<<dim3(N / 4, B), t256, 0, stream>>>(xt1, 128 * N, xt1, 128 * N, 64, N, N, K, idxK);
  gemmPS_kernel<<<dim3(N / 64, 1, B), t256, 0, stream>>>(xt1, 128 * N, 64, N, W2, 128, 64, Pt, St);
  ecfinish_kernel<<<dim3(N / 4, B), dim3(64, 4), 0, stream>>>(Pt, St, idxK, K, 64, N, g2, b2,
                                                              xt1 + (size_t)64 * N, (long)128 * N);

  // ---- vf partials
  gemm_colmax_kernel<<<dim3(N / 64, 1024 / 64, B), t256, 0, stream>>>(xt1, 128 * N, 128, N, W2m, 128, 1024,
                                                                      g2m, b2m, partA);

  // ---- aggregate knn (node1 vs xyz), then fused xm fill
  knn4_kernel<8><<<dim3(M / 4, B), t256, 0, stream>>>(node1, 3 * M, x, 3 * N, 3, M, N, K, idxK);
  xmfill_kernel<<<dim3((B * 128 * M + 255) / 256), t256, 0, stream>>>(xt1, N, fpsI, idxK, K, M, xm, B);

  // ---- stage 3: knn(xm) + edge_conv3 -> xc ch 0..255
  knn4_kernel<2><<<dim3(M / 4, B), t256, 0, stream>>>(xm, 256 * M, xm, 256 * M, 256, M, M, K2, idxK);
  gemmPS_kernel<<<dim3(M / 64, 256 / 64, B), t256, 0, stream>>>(xm, 256 * M, 256, M, W3, 512, 256, Pt, St);
  ecfinish_kernel<<<dim3(M, B), dim3(256, 1), 0, stream>>>(Pt, St, idxK, K2, 256, M, g3, b3, xc, (long)512 * M);

  // ---- stage 4: knn(x3) + edge_conv4 -> xc ch 256..511
  knn4_kernel<2><<<dim3(M / 4, B), t256, 0, stream>>>(xc, 512 * M, xc, 512 * M, 256, M, M, K2, idxK);
  gemmPS_kernel<<<dim3(M / 64, 256 / 64, B), t256, 0, stream>>>(xc, 512 * M, 256, M, W4, 512, 256, Pt, St);
  ecfinish_kernel<<<dim3(M, B), dim3(256, 1), 0, stream>>>(Pt, St, idxK, K2, 256, M, g4, b4,
                                                           xc + (size_t)256 * M, (long)512 * M);

  // ---- vs partials
  gemm_colmax_kernel<<<dim3(M / 64, 1024 / 64, B), t256, 0, stream>>>(xc, 512 * M, 512, M, W5, 512, 1024,
                                                                      g5, b5, partB);

  // ---- head (fused colmax_finish + MLP)
  head_kernel<<<dim3(B), t256, 0, stream>>>(partA, N / 64, partB, M / 64,
                                            Wl1, g6, b6, Wl2, bl2, g7, b7, Wl3, bl3, logits);
}

// Round 4
// 1488.857 us; speedup vs baseline: 1.1744x; 1.1744x over previous
//
#include <hip/hip_runtime.h>

#define BN_SCALE 0.9999950000374997f  // 1/sqrt(1+1e-5)

// ---- DPP full-wave reductions (pattern validated in fps_kernel since R2) ----
template <int CTRL>
__device__ __forceinline__ float dpp_fmax_step(float v) {
  int xi = __builtin_bit_cast(int, v);
  int ti = __builtin_amdgcn_update_dpp(xi, xi, CTRL, 0xf, 0xf, false);  // invalid lanes -> old(=v)
  return fmaxf(v, __builtin_bit_cast(float, ti));
}
template <int CTRL>
__device__ __forceinline__ int dpp_imin_step(int v) {
  int t = __builtin_amdgcn_update_dpp(v, v, CTRL, 0xf, 0xf, false);    // invalid lanes -> old(=v)
  return (t < v) ? t : v;
}
__device__ __forceinline__ float wave_fmax(float v) {
  v = dpp_fmax_step<0x111>(v);  // row_shr:1
  v = dpp_fmax_step<0x112>(v);  // row_shr:2
  v = dpp_fmax_step<0x114>(v);  // row_shr:4
  v = dpp_fmax_step<0x118>(v);  // row_shr:8
  v = dpp_fmax_step<0x142>(v);  // row_bcast:15
  v = dpp_fmax_step<0x143>(v);  // row_bcast:31
  return __builtin_bit_cast(float, __builtin_amdgcn_readlane(__builtin_bit_cast(int, v), 63));
}
__device__ __forceinline__ int wave_imin(int v) {
  v = dpp_imin_step<0x111>(v);
  v = dpp_imin_step<0x112>(v);
  v = dpp_imin_step<0x114>(v);
  v = dpp_imin_step<0x118>(v);
  v = dpp_imin_step<0x142>(v);
  v = dpp_imin_step<0x143>(v);
  return __builtin_amdgcn_readlane(v, 63);
}

// ---------------- knn4: 4 queries/block.
// Dot phase: c-outer / m-inner register-blocked, uniform scalar q loads (unchanged from R3).
// Selection phase REWRITTEN: row held in NR=N/64 VGPRs per wave; per round a per-lane
// ascending strict-> scan (keeps smallest m on ties), DPP fmax for the wave max, then
// DPP i32-min over (best==gmax ? index : INT_MAX) -> smallest index among maxima.
// This reproduces the old butterfly's (ov>best)||(ov==best&&oi<bi) semantics exactly
// -> indices bit-identical. Winner removed by setting its register to -inf.
template <int R>
__global__ void knn4_kernel(const float* __restrict__ Q, int qStrideB,
                            const float* __restrict__ Xc, int cStrideB,
                            int C, int M, int N, int k, int* __restrict__ idxOut) {
  constexpr int NR = 4 * R;                          // values per lane in selection
  __shared__ float negd[4][R * 256];
  int b = blockIdx.y, q0 = blockIdx.x * 4, tid = threadIdx.x;
  const float* qb = Q + (long)b * qStrideB + q0;     // + c*M walks channels (uniform)
  const float* cb = Xc + (long)b * cStrideB;         // uniform
  float d0[R], d1[R], d2[R], d3[R], sq[R];
  #pragma unroll
  for (int i = 0; i < R; ++i) { d0[i] = d1[i] = d2[i] = d3[i] = sq[i] = 0.f; }
  for (int c = 0; c < C; ++c) {
    float4 q4 = *(const float4*)(qb + (long)c * M);  // uniform -> scalar load
    const float* pc = cb + (long)c * N;              // uniform base
    #pragma unroll
    for (int i = 0; i < R; ++i) {
      float xv = pc[tid + 256 * i];
      sq[i] = fmaf(xv, xv, sq[i]);
      d0[i] = fmaf(q4.x, xv, d0[i]);
      d1[i] = fmaf(q4.y, xv, d1[i]);
      d2[i] = fmaf(q4.z, xv, d2[i]);
      d3[i] = fmaf(q4.w, xv, d3[i]);
    }
  }
  #pragma unroll
  for (int i = 0; i < R; ++i) {
    int m = tid + 256 * i;
    negd[0][m] = 2.f * d0[i] - sq[i];
    negd[1][m] = 2.f * d1[i] - sq[i];
    negd[2][m] = 2.f * d2[i] - sq[i];
    negd[3][m] = 2.f * d3[i] - sq[i];
  }
  __syncthreads();
  int lane = tid & 63, w = tid >> 6;
  const float* row = negd[w];
  int* outp = idxOut + ((long)b * M + (q0 + w)) * k;
  float v[NR];
  #pragma unroll
  for (int i = 0; i < NR; ++i) v[i] = row[lane + 64 * i];   // conflict-free, once
  for (int kk = 0; kk < k; ++kk) {
    float best = -INFINITY; int ib = 0;
    #pragma unroll
    for (int i = 0; i < NR; ++i) {
      bool c = v[i] > best;                 // strict > : first (smallest m) kept on ties
      best = c ? v[i] : best;
      ib = c ? i : ib;
    }
    int bi = (best > -INFINITY) ? (lane + (ib << 6)) : N;   // all-removed lane -> N (orig sem)
    float gmax = wave_fmax(best);
    int cand = (best == gmax) ? bi : 0x7FFFFFFF;
    int big = wave_imin(cand);              // smallest index among global maxima (uniform)
    if (lane == 0) outp[kk] = big;
    int ri = big >> 6;                      // uniform
    bool mine = (lane == (big & 63));
    #pragma unroll
    for (int i = 0; i < NR; ++i)
      if (i == ri) v[i] = mine ? -INFINITY : v[i];          // i==ri uniform -> 1 cndmask
  }
}

// ---------------- gemmPS: one pass computes BOTH halves of the edge-conv weight ----------------
__global__ void gemmPS_kernel(const float* __restrict__ X, int xStrideB, int C, int Np,
                              const float* __restrict__ W, int ldw, int O,
                              float* __restrict__ PtT, float* __restrict__ StT) {
  __shared__ float Wp[16][65];
  __shared__ float Ws[16][65];
  __shared__ float Xt[16][65];
  int b = blockIdx.z;
  int n0 = blockIdx.x * 64, o0 = blockIdx.y * 64;
  int tid = threadIdx.x;
  int to = tid % 16, tn = tid / 16;
  float accP[4][4] = {}, accS[4][4] = {};
  for (int c0 = 0; c0 < C; c0 += 16) {
    for (int e = tid; e < 16 * 64; e += 256) {
      int oo = e / 16, kk = e % 16;
      int c = c0 + kk, o = o0 + oo;
      bool ok = (c < C && o < O);
      Wp[kk][oo] = ok ? W[(long)o * ldw + c] : 0.f;
      Ws[kk][oo] = ok ? W[(long)o * ldw + C + c] : 0.f;
    }
    for (int e = tid; e < 16 * 64; e += 256) {
      int kk = e / 64, nn = e % 64;
      int c = c0 + kk, n = n0 + nn;
      Xt[kk][nn] = (c < C && n < Np) ? X[(long)b * xStrideB + (long)c * Np + n] : 0.f;
    }
    __syncthreads();
    for (int kk = 0; kk < 16; ++kk) {
      float xv[4], wp[4], ws[4];
      for (int i = 0; i < 4; ++i) xv[i] = Xt[kk][tn + 16 * i];
      for (int j = 0; j < 4; ++j) { wp[j] = Wp[kk][to + 16 * j]; ws[j] = Ws[kk][to + 16 * j]; }
      for (int i = 0; i < 4; ++i)
        for (int j = 0; j < 4; ++j) {
          accP[i][j] = fmaf(xv[i], wp[j], accP[i][j]);
          accS[i][j] = fmaf(xv[i], ws[j], accS[i][j]);
        }
    }
    __syncthreads();
  }
  for (int i = 0; i < 4; ++i) {
    int n = n0 + tn + 16 * i;
    if (n >= Np) continue;
    for (int j = 0; j < 4; ++j) {
      int o = o0 + to + 16 * j;
      if (o < O) {
        long off = ((long)b * Np + n) * O + o;
        PtT[off] = accP[i][j];
        StT[off] = accS[i][j];
      }
    }
  }
}

// ---------------- ecfinish ----------------
__global__ void ecfinish_kernel(const float* __restrict__ Pt, const float* __restrict__ St,
                                const int* __restrict__ idx, int k, int O, int Np,
                                const float* __restrict__ g, const float* __restrict__ bb,
                                float* __restrict__ outp, long oStrideB) {
  int b = blockIdx.y;
  int n = blockIdx.x * blockDim.y + threadIdx.y;
  int o = threadIdx.x;
  const float* PtB = Pt + (long)b * Np * O;
  const float* StB = St + (long)b * Np * O;
  const int* ip = idx + ((long)b * Np + n) * k;
  float mx = -INFINITY, mn = INFINITY;
  for (int kk = 0; kk < k; ++kk) {
    float v = PtB[(long)ip[kk] * O + o];
    mx = fmaxf(mx, v); mn = fminf(mn, v);
  }
  float ctrP = PtB[(long)n * O + o];
  float ctrS = StB[(long)n * O + o];
  float gs = g[o] * BN_SCALE;
  float m = (gs >= 0.f) ? mx : mn;
  float h = (ctrS - ctrP + m) * gs + bb[o];
  outp[(long)b * oStrideB + (long)o * Np + n] = h >= 0.f ? h : 0.2f * h;
}

// ---------------- gemm_colmax ----------------
__global__ void gemm_colmax_kernel(const float* __restrict__ X, int xStrideB, int C, int Np,
                                   const float* __restrict__ W, int ldw, int O,
                                   const float* __restrict__ g, const float* __restrict__ bb,
                                   float* __restrict__ partial) {
  __shared__ float Wt[16][65];
  __shared__ float Xt[16][65];
  int b = blockIdx.z;
  int n0 = blockIdx.x * 64, o0 = blockIdx.y * 64;
  int tid = threadIdx.x;
  int to = tid % 16, tn = tid / 16;
  float acc[4][4] = {};
  for (int c0 = 0; c0 < C; c0 += 16) {
    for (int e = tid; e < 16 * 64; e += 256) {
      int oo = e / 16, kk = e % 16;
      int c = c0 + kk, o = o0 + oo;
      Wt[kk][oo] = (c < C && o < O) ? W[(long)o * ldw + c] : 0.f;
    }
    for (int e = tid; e < 16 * 64; e += 256) {
      int kk = e / 64, nn = e % 64;
      int c = c0 + kk, n = n0 + nn;
      Xt[kk][nn] = (c < C && n < Np) ? X[(long)b * xStrideB + (long)c * Np + n] : 0.f;
    }
    __syncthreads();
    for (int kk = 0; kk < 16; ++kk) {
      float xv[4], wv[4];
      for (int i = 0; i < 4; ++i) xv[i] = Xt[kk][tn + 16 * i];
      for (int j = 0; j < 4; ++j) wv[j] = Wt[kk][to + 16 * j];
      for (int i = 0; i < 4; ++i)
        for (int j = 0; j < 4; ++j) acc[i][j] = fmaf(xv[i], wv[j], acc[i][j]);
    }
    __syncthreads();
  }
  float vm[4];
  for (int j = 0; j < 4; ++j) {
    int o = o0 + to + 16 * j;
    float gs = g[o] * BN_SCALE, bo = bb[o];
    float m = -INFINITY;
    for (int i = 0; i < 4; ++i) {
      float h = acc[i][j] * gs + bo;
      h = h >= 0.f ? h : 0.2f * h;
      m = fmaxf(m, h);
    }
    vm[j] = m;
  }
  for (int j = 0; j < 4; ++j) Xt[tn][to + 16 * j] = vm[j];
  __syncthreads();
  for (int s = 8; s > 0; s >>= 1) {
    if (tn < s)
      for (int j = 0; j < 4; ++j)
        Xt[tn][to + 16 * j] = fmaxf(Xt[tn][to + 16 * j], Xt[tn + s][to + 16 * j]);
    __syncthreads();
  }
  if (tn == 0)
    for (int j = 0; j < 4; ++j) {
      int o = o0 + to + 16 * j;
      partial[((long)b * gridDim.x + blockIdx.x) * O + o] = Xt[0][to + 16 * j];
    }
}

// ---------------- FPS: latency-optimized (DPP argmax, reg-resident points, coord broadcast).
__global__ void __launch_bounds__(256, 1) fps_kernel(const float* __restrict__ xyz, int N, int M,
                                                     int* __restrict__ fpsIdx, float* __restrict__ node1) {
  #pragma clang fp contract(off)
  __shared__ float4 sp4[2048];   // point n at slot (n&7)*256 + (n>>3)
  __shared__ int fidx[512];
  __shared__ float4 wvc[2][4];   // per-wave {gmax, x, y, z}, parity double-buffered
  __shared__ int   wis[2][4];
  int b = blockIdx.x, tid = threadIdx.x;
  int lane = tid & 63, w = tid >> 6;
  const float* xb = xyz + (long)b * 3 * N;
  for (int n = tid; n < N; n += 256) {
    sp4[((n & 7) << 8) | (n >> 3)] = make_float4(xb[n], xb[N + n], xb[2 * N + n], 0.f);
  }
  __syncthreads();
  float4 pt[8];
  #pragma unroll
  for (int i = 0; i < 8; ++i) pt[i] = sp4[(i << 8) | tid];   // point tid*8+i, resident in VGPRs
  float dist[8];
  #pragma unroll
  for (int i = 0; i < 8; ++i) dist[i] = 1e10f;
  int base = tid * 8;
  int last = 0;
  float4 l0 = sp4[0];            // point 0 (slot 0), broadcast read once
  float lx = l0.x, ly = l0.y, lz = l0.z;
  for (int it = 0; it < M; ++it) {
    int p = it & 1;
    if (tid == 0) fidx[it] = last;
    float best = -INFINITY; int bi = N;
    #pragma unroll
    for (int i = 0; i < 8; ++i) {
      float dx = pt[i].x - lx, dy = pt[i].y - ly, dz = pt[i].z - lz;
      float dx2 = dx * dx, dy2 = dy * dy, dz2 = dz * dz;
      float d = (dx2 + dy2) + dz2;
      float dn = dist[i];
      if (d < dn) dn = d;
      dist[i] = dn;
      if (dn > best) { best = dn; bi = base + i; }  // ascending -> first max in lane kept
    }
    // per-thread coords of its own best point (register select; off critical path)
    float cx = pt[0].x, cy = pt[0].y, cz = pt[0].z;
    #pragma unroll
    for (int i = 1; i < 8; ++i) {
      bool c = (bi == base + i);
      cx = c ? pt[i].x : cx; cy = c ? pt[i].y : cy; cz = c ? pt[i].z : cz;
    }
    // wave-wide exact max via DPP chain; full max lands in lane 63
    float v = best;
    v = dpp_fmax_step<0x111>(v);
    v = dpp_fmax_step<0x112>(v);
    v = dpp_fmax_step<0x114>(v);
    v = dpp_fmax_step<0x118>(v);
    v = dpp_fmax_step<0x142>(v);
    v = dpp_fmax_step<0x143>(v);
    float gmax = __builtin_bit_cast(float, __builtin_amdgcn_readlane(__builtin_bit_cast(int, v), 63));
    unsigned long long mm = __ballot(best == gmax);
    int srcLane = (int)(__ffsll((long long)mm) - 1);   // wave's first-occurrence argmax lane
    if (lane == srcLane) { wvc[p][w] = make_float4(gmax, cx, cy, cz); wis[p][w] = bi; }
    __syncthreads();
    // all threads redundantly combine the 4 wave results (waves ascend in index)
    float4 c0 = wvc[p][0], c1 = wvc[p][1], c2 = wvc[p][2], c3 = wvc[p][3];
    int i0 = wis[p][0], i1 = wis[p][1], i2 = wis[p][2], i3 = wis[p][3];
    float bv = c0.x; int bbi = i0; lx = c0.y; ly = c0.z; lz = c0.w;
    { bool c = (c1.x > bv) || (c1.x == bv && i1 < bbi);
      bv = c ? c1.x : bv; bbi = c ? i1 : bbi; lx = c ? c1.y : lx; ly = c ? c1.z : ly; lz = c ? c1.w : lz; }
    { bool c = (c2.x > bv) || (c2.x == bv && i2 < bbi);
      bv = c ? c2.x : bv; bbi = c ? i2 : bbi; lx = c ? c2.y : lx; ly = c ? c2.z : ly; lz = c ? c2.w : lz; }
    { bool c = (c3.x > bv) || (c3.x == bv && i3 < bbi);
      bv = c ? c3.x : bv; bbi = c ? i3 : bbi; lx = c ? c3.y : lx; ly = c ? c3.z : ly; lz = c ? c3.w : lz; }
    last = bbi;
    // parity: slot p rewritten only in iter it+2, after barrier it+1 -> safe with 1 barrier
  }
  for (int e = tid; e < M; e += 256) fpsIdx[(long)b * M + e] = fidx[e];
  for (int e = tid; e < 3 * M; e += 256) {
    int c = e / M, i = e % M;
    int src = fidx[i];
    float4 ptc = sp4[((src & 7) << 8) | (src >> 3)];
    node1[(long)b * 3 * M + e] = (c == 0) ? ptc.x : (c == 1) ? ptc.y : ptc.z;
  }
}

// ---------------- xmfill: fused nf1 gather + aggregate gathermax ----------------
__global__ void xmfill_kernel(const float* __restrict__ xt1, int N,
                              const int* __restrict__ fpsI,
                              const int* __restrict__ idxK, int k, int M,
                              float* __restrict__ xm, int B) {
  long t = (long)blockIdx.x * blockDim.x + threadIdx.x;
  long total = (long)B * 128 * M;
  if (t >= total) return;
  int i = (int)(t % M);
  int c = (int)((t / M) % 128);
  int b = (int)(t / ((long)128 * M));
  const float* xb = xt1 + (long)b * 128 * N + (long)c * N;
  float* xmB = xm + (long)b * 256 * M;
  xmB[(long)c * M + i] = xb[fpsI[(long)b * M + i]];
  const int* ip = idxK + ((long)b * M + i) * k;
  float best = -INFINITY;
  for (int kk = 0; kk < k; ++kk) best = fmaxf(best, xb[ip[kk]]);
  xmB[(long)(128 + c) * M + i] = best;
}

// ---------------- head: fused colmax_finish + 3-layer MLP ----------------
__global__ void head_kernel(const float* __restrict__ partA, int NTa,
                            const float* __restrict__ partB, int NTb,
                            const float* __restrict__ Wl1, const float* __restrict__ g6, const float* __restrict__ b6,
                            const float* __restrict__ Wl2, const float* __restrict__ bl2,
                            const float* __restrict__ g7, const float* __restrict__ b7,
                            const float* __restrict__ Wl3, const float* __restrict__ bl3,
                            float* __restrict__ logits) {
  __shared__ float v[2048];
  __shared__ float h1[512];
  __shared__ float h2[256];
  int b = blockIdx.x, tid = threadIdx.x;
  for (int o = tid; o < 1024; o += 256) {
    float m = -INFINITY;
    for (int t = 0; t < NTa; ++t) m = fmaxf(m, partA[((long)b * NTa + t) * 1024 + o]);
    v[o] = m;
    float m2 = -INFINITY;
    for (int t = 0; t < NTb; ++t) m2 = fmaxf(m2, partB[((long)b * NTb + t) * 1024 + o]);
    v[1024 + o] = m2;
  }
  __syncthreads();
  for (int o = tid; o < 512; o += 256) {
    const float* wr = Wl1 + (long)o * 2048;
    float s = 0.f;
    for (int c = 0; c < 2048; c += 4) {
      float4 w4 = *(const float4*)(wr + c);
      s = fmaf(w4.x, v[c], s); s = fmaf(w4.y, v[c + 1], s);
      s = fmaf(w4.z, v[c + 2], s); s = fmaf(w4.w, v[c + 3], s);
    }
    float h = s * (g6[o] * BN_SCALE) + b6[o];
    h1[o] = h >= 0.f ? h : 0.2f * h;
  }
  __syncthreads();
  for (int o = tid; o < 256; o += 256) {
    const float* wr = Wl2 + (long)o * 512;
    float s = 0.f;
    for (int c = 0; c < 512; c += 4) {
      float4 w4 = *(const float4*)(wr + c);
      s = fmaf(w4.x, h1[c], s); s = fmaf(w4.y, h1[c + 1], s);
      s = fmaf(w4.z, h1[c + 2], s); s = fmaf(w4.w, h1[c + 3], s);
    }
    s += bl2[o];
    float h = s * (g7[o] * BN_SCALE) + b7[o];
    h2[o] = h >= 0.f ? h : 0.2f * h;
  }
  __syncthreads();
  if (tid < 40) {
    const float* wr = Wl3 + (long)tid * 256;
    float s = 0.f;
    for (int c = 0; c < 256; ++c) s = fmaf(wr[c], h2[c], s);
    logits[(long)b * 40 + tid] = s + bl3[tid];
  }
}

extern "C" void kernel_launch(void* const* d_in, const int* in_sizes, int n_in,
                              void* d_out, int out_size, void* d_ws, size_t ws_size,
                              hipStream_t stream) {
  const float* x   = (const float*)d_in[0];
  const float* W1  = (const float*)d_in[1];
  const float* g1  = (const float*)d_in[2];
  const float* b1  = (const float*)d_in[3];
  const float* W2  = (const float*)d_in[4];
  const float* g2  = (const float*)d_in[5];
  const float* b2  = (const float*)d_in[6];
  const float* W2m = (const float*)d_in[7];
  const float* g2m = (const float*)d_in[8];
  const float* b2m = (const float*)d_in[9];
  const float* W3  = (const float*)d_in[10];
  const float* g3  = (const float*)d_in[11];
  const float* b3  = (const float*)d_in[12];
  const float* W4  = (const float*)d_in[13];
  const float* g4  = (const float*)d_in[14];
  const float* b4  = (const float*)d_in[15];
  const float* W5  = (const float*)d_in[16];
  const float* g5  = (const float*)d_in[17];
  const float* b5  = (const float*)d_in[18];
  const float* Wl1 = (const float*)d_in[19];
  const float* g6  = (const float*)d_in[20];
  const float* b6  = (const float*)d_in[21];
  const float* Wl2 = (const float*)d_in[22];
  const float* bl2 = (const float*)d_in[23];
  const float* g7  = (const float*)d_in[24];
  const float* b7  = (const float*)d_in[25];
  const float* Wl3 = (const float*)d_in[26];
  const float* bl3 = (const float*)d_in[27];
  float* outF = (float*)d_out;

  const int B = 8, N = 2048, K = 20, M = 512, K2 = 10;

  float* ws    = (float*)d_ws;
  float* xt1   = ws;                               // (B,128,N)
  float* xm    = xt1 + (size_t)B * 128 * N;        // (B,256,M)
  float* xc    = xm  + (size_t)B * 256 * M;        // (B,512,M)
  float* Pt    = xc  + (size_t)B * 512 * M;        // max(B*N*64, B*M*256)
  float* St    = Pt  + (size_t)B * N * 64;
  float* partA = St  + (size_t)B * N * 64;         // (B,32,1024)
  float* partB = partA + (size_t)B * 32 * 1024;    // (B,8,1024)
  int*   idxK  = (int*)(partB + (size_t)B * 8 * 1024);  // (B,N,K)
  int*   fpsI  = idxK + (size_t)B * N * K;         // (B,M)

  float* logits = outF;        // (B,40)
  float* node1  = outF + 320;  // (B,3,M)

  dim3 t256(256);

  // ---- stage 1: knn(xyz) + edge_conv1 -> xt1 ch 0..63
  knn4_kernel<8><<<dim3(N / 4, B), t256, 0, stream>>>(x, 3 * N, x, 3 * N, 3, N, N, K, idxK);
  gemmPS_kernel<<<dim3(N / 64, 1, B), t256, 0, stream>>>(x, 3 * N, 3, N, W1, 6, 64, Pt, St);
  ecfinish_kernel<<<dim3(N / 4, B), dim3(64, 4), 0, stream>>>(Pt, St, idxK, K, 64, N, g1, b1, xt1, (long)128 * N);

  // FPS (xyz only)
  fps_kernel<<<dim3(B), t256, 0, stream>>>(x, N, M, fpsI, node1);

  // ---- stage 2: knn(x1) + edge_conv2 -> xt1 ch 64..127
  knn4_kernel<8><<<dim3(N / 4, B), t256, 0, stream>>>(xt1, 128 * N, xt1, 128 * N, 64, N, N, K, idxK);
  gemmPS_kernel<<<dim3(N / 64, 1, B), t256, 0, stream>>>(xt1, 128 * N, 64, N, W2, 128, 64, Pt, St);
  ecfinish_kernel<<<dim3(N / 4, B), dim3(64, 4), 0, stream>>>(Pt, St, idxK, K, 64, N, g2, b2,
                                                              xt1 + (size_t)64 * N, (long)128 * N);

  // ---- vf partials
  gemm_colmax_kernel<<<dim3(N / 64, 1024 / 64, B), t256, 0, stream>>>(xt1, 128 * N, 128, N, W2m, 128, 1024,
                                                                      g2m, b2m, partA);

  // ---- aggregate knn (node1 vs xyz), then fused xm fill
  knn4_kernel<8><<<dim3(M / 4, B), t256, 0, stream>>>(node1, 3 * M, x, 3 * N, 3, M, N, K, idxK);
  xmfill_kernel<<<dim3((B * 128 * M + 255) / 256), t256, 0, stream>>>(xt1, N, fpsI, idxK, K, M, xm, B);

  // ---- stage 3: knn(xm) + edge_conv3 -> xc ch 0..255
  knn4_kernel<2><<<dim3(M / 4, B), t256, 0, stream>>>(xm, 256 * M, xm, 256 * M, 256, M, M, K2, idxK);
  gemmPS_kernel<<<dim3(M / 64, 256 / 64, B), t256, 0, stream>>>(xm, 256 * M, 256, M, W3, 512, 256, Pt, St);
  ecfinish_kernel<<<dim3(M, B), dim3(256, 1), 0, stream>>>(Pt, St, idxK, K2, 256, M, g3, b3, xc, (long)512 * M);

  // ---- stage 4: knn(x3) + edge_conv4 -> xc ch 256..511
  knn4_kernel<2><<<dim3(M / 4, B), t256, 0, stream>>>(xc, 512 * M, xc, 512 * M, 256, M, M, K2, idxK);
  gemmPS_kernel<<<dim3(M / 64, 256 / 64, B), t256, 0, stream>>>(xc, 512 * M, 256, M, W4, 512, 256, Pt, St);
  ecfinish_kernel<<<dim3(M, B), dim3(256, 1), 0, stream>>>(Pt, St, idxK, K2, 256, M, g4, b4,
                                                           xc + (size_t)256 * M, (long)512 * M);

  // ---- vs partials
  gemm_colmax_kernel<<<dim3(M / 64, 1024 / 64, B), t256, 0, stream>>>(xc, 512 * M, 512, M, W5, 512, 1024,
                                                                      g5, b5, partB);

  // ---- head (fused colmax_finish + MLP)
  head_kernel<<<dim3(B), t256, 0, stream>>>(partA, N / 64, partB, M / 64,
                                            Wl1, g6, b6, Wl2, bl2, g7, b7, Wl3, bl3, logits);
}